// Round 9
// baseline (1300.771 us; speedup 1.0000x reference)
//
#include <hip/hip_runtime.h>
#include <math.h>

constexpr int B_ = 4, C_ = 60, H_ = 384, W_ = 384;
constexpr int HW_ = H_ * W_;
constexpr int NC_ = B_ * C_ * HW_;   // 35,389,440
constexpr int NE_ = B_ * 120 * HW_;  // 70,778,880

typedef __attribute__((ext_vector_type(8))) short short8;
typedef __attribute__((ext_vector_type(4))) float f32x4;
typedef __attribute__((ext_vector_type(4))) unsigned short u16x4;

__device__ __forceinline__ unsigned short f2b(float f) {
    unsigned u = __builtin_bit_cast(unsigned, f);
    unsigned r = (u + 0x7fff + ((u >> 16) & 1)) >> 16;
    return (unsigned short)r;
}
__device__ __forceinline__ float b2f(unsigned short s) {
    return __builtin_bit_cast(float, (unsigned)s << 16);
}

// ---------------------------------------------------------------------------
// Weight prep: fp32 [COUT][CIN] -> bf16 [MP][KP], zero-pad, XOR-swizzle
// ---------------------------------------------------------------------------
struct PrepJobs {
    const float* src[8];
    unsigned short* dst[8];
    int cin[8];
    int cout[8];
};

__global__ __launch_bounds__(256) void prep_all(PrepJobs J)
{
    int bid = blockIdx.x;
    #pragma unroll 1
    for (int j = 0; j < 8; ++j) {
        const int KP = J.cin[j]  > 64 ? 128 : 64;
        const int MP = J.cout[j] > 64 ? 128 : 64;
        const int nb = MP * KP / 256;
        if (bid < nb) {
            const int i = bid * 256 + threadIdx.x;
            const int o = i / KP, c = i - o * KP;
            const float v = (o < J.cout[j] && c < J.cin[j]) ? J.src[j][o * J.cin[j] + c] : 0.f;
            J.dst[j][o * KP + (c ^ ((o & 7) << 3))] = f2b(v);
            return;
        }
        bid -= nb;
    }
}

// ---------------------------------------------------------------------------
// Epilogue affine prep: fold bias (+BN) into per-channel A*acc + B.
// ---------------------------------------------------------------------------
struct ABJobs {
    const float* bias[8];
    const float* g[8];
    const float* bb[8];
    const float* m[8];
    const float* v[8];
    float* dst[8];
    int cout[8];
};

__global__ __launch_bounds__(256) void prep_ab(ABJobs J)
{
    const int j = blockIdx.x;
    const int n = J.cout[j];
    for (int o = threadIdx.x; o < n; o += 256) {
        float A = 1.f, Bv = J.bias[j][o];
        if (J.g[j]) {
            const float s = J.g[j][o] * rsqrtf(J.v[j][o] + 1e-5f);
            A  = s;
            Bv = (Bv - J.m[j][o]) * s + J.bb[j][o];
        }
        J.dst[j][o]     = A;
        J.dst[j][n + o] = Bv;
    }
}

// ---------------------------------------------------------------------------
// conv1x1 via MFMA, 128-px tile, 4 waves. D = [px][ch] orientation.
// ---------------------------------------------------------------------------
template<int KP>
__device__ __forceinline__ int lds_off(int px, int cb) {
    return px * (KP * 2) + (cb ^ ((px & 7) << 4) ^ (((px >> 3) & 1) << 6));
}

template<int CIN, int COUT, int GSH, bool SRCB, bool RELU, bool RESID,
         bool RESIDB, bool OUTB>
__global__ __launch_bounds__(256, 4)
void conv_g(const void* __restrict__ in_, const unsigned short* __restrict__ wp,
            const float* __restrict__ AB,
            const void* __restrict__ resid_, void* __restrict__ out_)
{
    constexpr int KP  = CIN  > 64 ? 128 : 64;
    constexpr int MP  = COUT > 64 ? 128 : 64;
    constexpr int NNT = MP / 16;
    constexpr int KBL = KP / 32;
    __shared__ __align__(16) char xlds[128 * KP * 2];

    const int tid = threadIdx.x;
    const int n0  = blockIdx.x * 128;
    const int b   = n0 / HW_;
    const int p0  = n0 - b * HW_;
    const int hh  = p0 / W_;
    const int ww0 = p0 - hh * W_;

    // ---- staging: task = (oct | pr); pr in low 4 bits ----
    for (int task = tid; task < (KP / 2) * 16; task += 256) {
        const int oct = (task >> 4) & 15;
        const int pr  = (task & 15) | ((task >> 8) << 4);
        const int c0  = pr * 2;
        const int s0  = oct * 8;

        if (c0 >= CIN) {
            #pragma unroll
            for (int i = 0; i < 8; ++i)
                *(unsigned*)(xlds + lds_off<KP>(s0 + i, c0 * 2)) = 0u;
            continue;
        }

        int dh = 0, dw = 0;
        if (GSH > 0) {
            const int grp = c0 / GSH;
            dh = (grp == 2) ? 1 : ((grp == 3) ? -1 : 0);
            dw = (grp == 0) ? 1 : ((grp == 1) ? -1 : 0);
        }
        const int h2 = hh + dh;
        const bool vh = (unsigned)h2 < (unsigned)H_;
        const long eoff = (long)(b * CIN + c0) * HW_ + h2 * W_ + ww0 + s0;

        unsigned short va[8], vb[8];
        if (vh) {
            if constexpr (SRCB) {
                const unsigned short* p = (const unsigned short*)in_;
                short8 A = *(const short8*)(p + eoff);
                short8 Bv = *(const short8*)(p + eoff + HW_);
                #pragma unroll
                for (int i = 0; i < 8; ++i) { va[i] = (unsigned short)A[i]; vb[i] = (unsigned short)Bv[i]; }
            } else {
                const float* p = (const float*)in_;
                f32x4 A0 = *(const f32x4*)(p + eoff);
                f32x4 A1 = *(const f32x4*)(p + eoff + 4);
                f32x4 B0 = *(const f32x4*)(p + eoff + HW_);
                f32x4 B1 = *(const f32x4*)(p + eoff + HW_ + 4);
                #pragma unroll
                for (int i = 0; i < 4; ++i) {
                    va[i] = f2b(A0[i]); va[i + 4] = f2b(A1[i]);
                    vb[i] = f2b(B0[i]); vb[i + 4] = f2b(B1[i]);
                }
            }
        } else {
            #pragma unroll
            for (int i = 0; i < 8; ++i) { va[i] = 0; vb[i] = 0; }
        }
        #pragma unroll
        for (int i = 0; i < 8; ++i) {
            const int px = s0 + i - dw;
            if ((unsigned)px < 128u) {
                const unsigned v = (unsigned)va[i] | ((unsigned)vb[i] << 16);
                *(unsigned*)(xlds + lds_off<KP>(px, c0 * 2)) = v;
            }
        }
        if (GSH > 0 && dw != 0) {
            const bool hndl = (dw == 1) ? (oct == 15) : (oct == 0);
            if (hndl) {
                const int px_e = (dw == 1) ? 127 : 0;
                const int w_abs = ww0 + px_e + dw;
                unsigned short ua = 0, ub = 0;
                if (vh && (unsigned)w_abs < (unsigned)W_) {
                    const long e2 = (long)(b * CIN + c0) * HW_ + h2 * W_ + w_abs;
                    if constexpr (SRCB) {
                        ua = ((const unsigned short*)in_)[e2];
                        ub = ((const unsigned short*)in_)[e2 + HW_];
                    } else {
                        ua = f2b(((const float*)in_)[e2]);
                        ub = f2b(((const float*)in_)[e2 + HW_]);
                    }
                }
                *(unsigned*)(xlds + lds_off<KP>(px_e, c0 * 2)) =
                    (unsigned)ua | ((unsigned)ub << 16);
            }
        }
    }
    __syncthreads();

    // ---- MFMA: A = X from LDS (px rows), B = W from global (ch rows) ----
    const int wv = tid >> 6, lo = tid & 15, hi = (tid & 63) >> 4;
    f32x4 acc[2][NNT];
    #pragma unroll
    for (int mt = 0; mt < 2; ++mt)
        #pragma unroll
        for (int nt = 0; nt < NNT; ++nt) acc[mt][nt] = f32x4{0.f, 0.f, 0.f, 0.f};

    #pragma unroll
    for (int kb = 0; kb < KBL; ++kb) {
        short8 a[2], bb[NNT];
        #pragma unroll
        for (int mt = 0; mt < 2; ++mt) {
            const int row = wv * 32 + mt * 16 + lo;
            a[mt] = *(const short8*)(xlds + lds_off<KP>(row, kb * 64 + hi * 16));
        }
        #pragma unroll
        for (int nt = 0; nt < NNT; ++nt) {
            const int row = nt * 16 + lo;
            bb[nt] = *(const short8*)((const char*)wp +
                      row * (KP * 2) + ((kb * 64 + hi * 16) ^ ((row & 7) << 4)));
        }
        #pragma unroll
        for (int mt = 0; mt < 2; ++mt)
            #pragma unroll
            for (int nt = 0; nt < NNT; ++nt)
                acc[mt][nt] = __builtin_amdgcn_mfma_f32_16x16x32_bf16(
                    a[mt], bb[nt], acc[mt][nt], 0, 0, 0);
    }

    // ---- epilogue: lane holds 4 consecutive px of channel nt*16+lo ----
    #pragma unroll
    for (int mt = 0; mt < 2; ++mt) {
        const int px0 = p0 + wv * 32 + mt * 16 + hi * 4;
        #pragma unroll
        for (int nt = 0; nt < NNT; ++nt) {
            const int ch = nt * 16 + lo;
            if (ch < COUT) {
                const long oi = (long)(b * COUT + ch) * HW_ + px0;
                float v[4];
                f32x4 rf;
                u16x4 rb;
                if (RESID) {
                    if (RESIDB) rb = *(const u16x4*)((const unsigned short*)resid_ + oi);
                    else        rf = *(const f32x4*)((const float*)resid_ + oi);
                }
                #pragma unroll
                for (int r = 0; r < 4; ++r) {
                    float t = fmaf(acc[mt][nt][r], AB[ch], AB[COUT + ch]);
                    if (RELU) t = fmaxf(t, 0.f);
                    if (RESID) t += RESIDB ? b2f(rb[r]) : rf[r];
                    v[r] = t;
                }
                if (OUTB) {
                    u16x4 o4;
                    #pragma unroll
                    for (int r = 0; r < 4; ++r) o4[r] = f2b(v[r]);
                    *(u16x4*)((unsigned short*)out_ + oi) = o4;
                } else {
                    *(f32x4*)((float*)out_ + oi) = f32x4{v[0], v[1], v[2], v[3]};
                }
            }
        }
    }
}

// ---------------------------------------------------------------------------
// MFMA window attention. Vectorized gather: task = (win,tensor,ch,wrow,g)
// with aligned-4px group g fastest -> adjacent lanes read contiguous 8B
// chunks of one window row. Wrap windows take a scalar fallback.
// ---------------------------------------------------------------------------
template<int WS, int WPB>
__global__ __launch_bounds__(256)
void attn_m(const unsigned short* __restrict__ qsrc, int qC, int qbase,
            const unsigned short* __restrict__ vsrc, int vC, int vbase,
            unsigned short* __restrict__ out, int obase)
{
    constexpr int P     = WS * WS;
    constexpr int NMT   = P / 16;
    constexpr int S     = WS / 2;
    constexpr int WGX   = W_ / WS;
    constexpr int WGY   = H_ / WS;
    constexpr int NWIN  = WGY * WGX;
    constexpr int QP    = 40;
    constexpr int KP2   = ((P + 31) / 32) * 32;
    constexpr int VP    = KP2 + 8;
    constexpr int KB2   = KP2 / 32;
    constexpr int TILES = WPB * NMT;
    constexpr int NG    = (WS + 6) / 4;     // aligned 4-px groups per row

    __shared__ __align__(16) unsigned short Qs[WPB * P * QP];
    __shared__ __align__(16) unsigned short VTs[WPB * 32 * VP];
    __shared__ __align__(16) unsigned short Ps[WPB * P * VP];
    __shared__ float rs[WPB * P];

    const int tid = threadIdx.x;

    // ---- zero pads ----
    for (int i = tid; i < WPB * P * 6; i += 256) {
        const int row = i / 6, j = i - (i / 6) * 6;
        *(unsigned*)&Qs[row * QP + 20 + 2 * j] = 0u;
    }
    for (int i = tid; i < WPB * 12 * (KP2 / 2); i += 256) {
        const int rr = i / (KP2 / 2), j = i - rr * (KP2 / 2);
        const int win = rr / 12, ch = 20 + (rr - (rr / 12) * 12);
        *(unsigned*)&VTs[(win * 32 + ch) * VP + 2 * j] = 0u;
    }
    if constexpr (KP2 > P) {
        for (int i = tid; i < WPB * 20 * ((KP2 - P) / 2); i += 256) {
            const int rr = i / ((KP2 - P) / 2), j = i - rr * ((KP2 - P) / 2);
            const int win = rr / 20, ch = rr - (rr / 20) * 20;
            *(unsigned*)&VTs[(win * 32 + ch) * VP + P + 2 * j] = 0u;
        }
        for (int i = tid; i < WPB * P * ((KP2 - P) / 2); i += 256) {
            const int row = i / ((KP2 - P) / 2), j = i - row * ((KP2 - P) / 2);
            *(unsigned*)&Ps[row * VP + P + 2 * j] = 0u;
        }
    }

    // ---- vectorized gather ----
    for (int t = tid; t < WPB * 2 * 20 * WS * NG; t += 256) {
        int r = t;
        const int g    = r % NG; r /= NG;
        const int wrow = r % WS; r /= WS;
        const int ch   = r % 20; r /= 20;
        const int tens = r & 1;  r >>= 1;
        const int win  = r;

        const int gw   = blockIdx.x * WPB + win;
        const int b    = gw / NWIN;
        const int rwin = gw - b * NWIN;
        const int wh   = rwin / WGX, ww = rwin - (rwin / WGX) * WGX;
        int hs = wh * WS + wrow + S; if (hs >= H_) hs -= H_;
        const int c0 = ww * WS + S;
        const unsigned short* src = tens ? vsrc : qsrc;
        const int cc = tens ? (vC * b + vbase) : (qC * b + qbase);
        const long rowbase = (long)(cc + ch) * HW_ + (long)hs * W_;

        if (c0 + WS <= W_) {
            const int col0 = (c0 & ~3) + 4 * g;
            const u16x4 v4 = *(const u16x4*)(src + rowbase + col0);
            #pragma unroll
            for (int e = 0; e < 4; ++e) {
                const int pc = col0 + e - c0;
                if ((unsigned)pc < (unsigned)WS) {
                    const int pos = wrow * WS + pc;
                    if (tens) VTs[(win * 32 + ch) * VP + pos] = v4[e];
                    else      Qs [(win * P + pos) * QP + ch]  = v4[e];
                }
            }
        } else if (g == 0) {        // wrap window: whole row scalar
            for (int pc = 0; pc < WS; ++pc) {
                int wd = c0 + pc; if (wd >= W_) wd -= W_;
                const unsigned short u = src[rowbase + wd];
                const int pos = wrow * WS + pc;
                if (tens) VTs[(win * 32 + ch) * VP + pos] = u;
                else      Qs [(win * P + pos) * QP + ch]  = u;
            }
        }
    }
    __syncthreads();

    const int wv = tid >> 6, lo = tid & 15, hi = (tid & 63) >> 4;

    // ---- phase 1: S = QQ^T, P = exp(S), rowsums ----
    for (int t = wv; t < TILES; t += 4) {
        const int win = t / NMT, mt = t - (t / NMT) * NMT;
        const unsigned short* Qw = Qs + win * P * QP;
        unsigned short* Pw = Ps + win * P * VP;

        const short8 af = *(const short8*)(Qw + (mt * 16 + lo) * QP + hi * 8);
        f32x4 a1[NMT];
        #pragma unroll
        for (int nt = 0; nt < NMT; ++nt) a1[nt] = f32x4{0.f, 0.f, 0.f, 0.f};
        #pragma unroll
        for (int nt = 0; nt < NMT; ++nt) {
            const short8 bf = *(const short8*)(Qw + (nt * 16 + lo) * QP + hi * 8);
            a1[nt] = __builtin_amdgcn_mfma_f32_16x16x32_bf16(af, bf, a1[nt], 0, 0, 0);
        }
        float psum[4] = {0.f, 0.f, 0.f, 0.f};
        #pragma unroll
        for (int nt = 0; nt < NMT; ++nt) {
            #pragma unroll
            for (int r = 0; r < 4; ++r) {
                const float p = __expf(a1[nt][r]);
                psum[r] += p;
                Pw[(mt * 16 + hi * 4 + r) * VP + nt * 16 + lo] = f2b(p);
            }
        }
        #pragma unroll
        for (int r = 0; r < 4; ++r) {
            psum[r] += __shfl_xor(psum[r], 1);
            psum[r] += __shfl_xor(psum[r], 2);
            psum[r] += __shfl_xor(psum[r], 4);
            psum[r] += __shfl_xor(psum[r], 8);
        }
        if (lo == 0) {
            #pragma unroll
            for (int r = 0; r < 4; ++r)
                rs[win * P + mt * 16 + hi * 4 + r] = psum[r];
        }
    }
    __syncthreads();

    // ---- phase 2: D = [ch][query]; A = VT (ch rows), B = P (query rows) ----
    for (int t = wv; t < TILES; t += 4) {
        const int win = t / NMT, qt = t - (t / NMT) * NMT;
        const unsigned short* Vw = VTs + win * 32 * VP;
        const unsigned short* Pw = Ps + win * P * VP;

        f32x4 a2[2];
        a2[0] = f32x4{0.f, 0.f, 0.f, 0.f};
        a2[1] = f32x4{0.f, 0.f, 0.f, 0.f};
        #pragma unroll
        for (int kb = 0; kb < KB2; ++kb) {
            const short8 bf = *(const short8*)(Pw + (qt * 16 + lo) * VP + kb * 32 + hi * 8);
            #pragma unroll
            for (int m2 = 0; m2 < 2; ++m2) {
                const short8 af = *(const short8*)(Vw + (m2 * 16 + lo) * VP + kb * 32 + hi * 8);
                a2[m2] = __builtin_amdgcn_mfma_f32_16x16x32_bf16(af, bf, a2[m2], 0, 0, 0);
            }
        }
        const int gw = blockIdx.x * WPB + win;
        const int b  = gw / NWIN;
        const int rwin = gw - b * NWIN;
        const int wh = rwin / WGX, ww = rwin - (rwin / WGX) * WGX;

        const int row = qt * 16 + lo;
        const float inv = 1.f / rs[win * P + row];
        const int pr = row / WS, pc = row - (row / WS) * WS;
        int hs = wh * WS + pr + S; if (hs >= H_) hs -= H_;
        int wd = ww * WS + pc + S; if (wd >= W_) wd -= W_;
        const long pbase = (long)(b * 60 + obase) * HW_ + (long)hs * W_ + wd;
        #pragma unroll
        for (int m2 = 0; m2 < 2; ++m2) {
            #pragma unroll
            for (int r = 0; r < 4; ++r) {
                const int ch = m2 * 16 + hi * 4 + r;
                if (ch < 20)
                    out[pbase + (long)ch * HW_] = f2b(a2[m2][r] * inv);
            }
        }
    }
}

// ---------------------------------------------------------------------------
extern "C" void kernel_launch(void* const* d_in, const int* in_sizes, int n_in,
                              void* d_out, int out_size, void* d_ws, size_t ws_size,
                              hipStream_t stream)
{
    const float* x     = (const float*)d_in[0];
    const float* l0w0  = (const float*)d_in[1];
    const float* l0b0  = (const float*)d_in[2];
    const float* l0w1  = (const float*)d_in[3];
    const float* l0b1  = (const float*)d_in[4];
    const float* g0piw = (const float*)d_in[5];
    const float* g0pib = (const float*)d_in[6];
    const float* g0bng = (const float*)d_in[7];
    const float* g0bnb = (const float*)d_in[8];
    const float* g0bnm = (const float*)d_in[9];
    const float* g0bnv = (const float*)d_in[10];
    const float* g0pow = (const float*)d_in[11];
    const float* g0pob = (const float*)d_in[12];
    const float* l1w0  = (const float*)d_in[13];
    const float* l1b0  = (const float*)d_in[14];
    const float* l1w1  = (const float*)d_in[15];
    const float* l1b1  = (const float*)d_in[16];
    const float* g1piw = (const float*)d_in[17];
    const float* g1pib = (const float*)d_in[18];
    const float* g1bng = (const float*)d_in[19];
    const float* g1bnb = (const float*)d_in[20];
    const float* g1bnm = (const float*)d_in[21];
    const float* g1bnv = (const float*)d_in[22];
    const float* g1pow = (const float*)d_in[23];
    const float* g1pob = (const float*)d_in[24];

    // ws: HID(NE_) | XPB(NE_) | XP1(NC_) | YS1(NC_) | CCB(NC_) | WP | AB
    unsigned short* HID = (unsigned short*)d_ws;
    unsigned short* XPB = HID + NE_;
    unsigned short* XP1 = XPB + NE_;
    unsigned short* YS1 = XP1 + NC_;
    unsigned short* CCB = YS1 + NC_;
    unsigned short* WP  = CCB + NC_;
    float*          ABF = (float*)(WP + 53248);
    float* OUTF  = (float*)d_out;
    unsigned short* YS0 = (unsigned short*)d_out;

    unsigned short* W1  = WP;
    unsigned short* W2  = WP + 8192;
    unsigned short* W3  = WP + 16384;
    unsigned short* W5  = WP + 24576;
    unsigned short* W6  = WP + 28672;
    unsigned short* W7  = WP + 36864;
    unsigned short* W8  = WP + 45056;
    unsigned short* W10 = WP + 49152;

    float* AB1  = ABF;
    float* AB2  = ABF + 240;
    float* AB3  = ABF + 360;
    float* AB5  = ABF + 600;
    float* AB6  = ABF + 720;
    float* AB7  = ABF + 960;
    float* AB8  = ABF + 1080;
    float* AB10 = ABF + 1200;

    PrepJobs J;
    J.src[0]=l0w0;  J.dst[0]=W1;  J.cin[0]=60;  J.cout[0]=120;
    J.src[1]=l0w1;  J.dst[1]=W2;  J.cin[1]=120; J.cout[1]=60;
    J.src[2]=g0piw; J.dst[2]=W3;  J.cin[2]=60;  J.cout[2]=120;
    J.src[3]=g0pow; J.dst[3]=W5;  J.cin[3]=60;  J.cout[3]=60;
    J.src[4]=l1w0;  J.dst[4]=W6;  J.cin[4]=60;  J.cout[4]=120;
    J.src[5]=l1w1;  J.dst[5]=W7;  J.cin[5]=120; J.cout[5]=60;
    J.src[6]=g1piw; J.dst[6]=W8;  J.cin[6]=60;  J.cout[6]=60;
    J.src[7]=g1pow; J.dst[7]=W10; J.cin[7]=60;  J.cout[7]=60;
    prep_all<<<208, 256, 0, stream>>>(J);

    ABJobs A;
    for (int j = 0; j < 8; ++j) { A.g[j]=nullptr; A.bb[j]=nullptr; A.m[j]=nullptr; A.v[j]=nullptr; }
    A.bias[0]=l0b0;  A.dst[0]=AB1;  A.cout[0]=120;
    A.bias[1]=l0b1;  A.dst[1]=AB2;  A.cout[1]=60;
    A.bias[2]=g0pib; A.dst[2]=AB3;  A.cout[2]=120; A.g[2]=g0bng; A.bb[2]=g0bnb; A.m[2]=g0bnm; A.v[2]=g0bnv;
    A.bias[3]=g0pob; A.dst[3]=AB5;  A.cout[3]=60;
    A.bias[4]=l1b0;  A.dst[4]=AB6;  A.cout[4]=120;
    A.bias[5]=l1b1;  A.dst[5]=AB7;  A.cout[5]=60;
    A.bias[6]=g1pib; A.dst[6]=AB8;  A.cout[6]=60;  A.g[6]=g1bng; A.bb[6]=g1bnb; A.m[6]=g1bnm; A.v[6]=g1bnv;
    A.bias[7]=g1pob; A.dst[7]=AB10; A.cout[7]=60;
    prep_ab<<<8, 256, 0, stream>>>(A);

    dim3 blk(256);
    dim3 gconv(B_ * HW_ / 128);   // 4608

    // template args: CIN, COUT, GSH, SRCB, RELU, RESID, RESIDB, OUTB
    // S1: hid0 = relu(conv(shift5(x)))            f32 -> bf16
    conv_g<60,120,12,false,true,false,false,true><<<gconv,blk,0,stream>>>(
        x, W1, AB1, nullptr, HID);
    // S2: x1 = conv(shift5(hid0)) + x             bf16+f32resid -> bf16 CCB
    conv_g<120,60,24,true,false,true,false,true><<<gconv,blk,0,stream>>>(
        HID, W2, AB2, x, CCB);
    // S3: xp0 = BN(pi0(x1)) -> XPB bf16 (120ch)
    conv_g<60,120,0,true,false,false,false,true><<<gconv,blk,0,stream>>>(
        CCB, W3, AB3, nullptr, XPB);
    // S4: gmsa_first attention -> YS0 (d_out scratch)
    attn_m<4,4><<<dim3(9216),blk,0,stream>>>(XPB,120,0,   XPB,120,20,  YS0, 0);
    attn_m<8,1><<<dim3(9216),blk,0,stream>>>(XPB,120,40,  XPB,120,60,  YS0,20);
    attn_m<12,1><<<dim3(4096),blk,0,stream>>>(XPB,120,80, XPB,120,100, YS0,40);
    // S5: x2 = po0(ys0) + x1                      bf16 -> bf16 CCB (in place)
    conv_g<60,60,0,true,false,true,true,true><<<gconv,blk,0,stream>>>(
        YS0, W5, AB5, CCB, CCB);
    // S6: hid1 = relu(conv(shift5(x2)))
    conv_g<60,120,12,true,true,false,false,true><<<gconv,blk,0,stream>>>(
        CCB, W6, AB6, nullptr, HID);
    // S7: x3 = conv(shift5(hid1)) + x2            (CCB in place)
    conv_g<120,60,24,true,false,true,true,true><<<gconv,blk,0,stream>>>(
        HID, W7, AB7, CCB, CCB);
    // S8: xp1 = BN(pi1(x3)) -> XP1 bf16 (60ch; XPB stays intact for S9 q)
    conv_g<60,60,0,true,false,false,false,true><<<gconv,blk,0,stream>>>(
        CCB, W8, AB8, nullptr, XP1);
    // S9: gmsa_shared attention (q from XPB xp0 q-channels, v from XP1)
    attn_m<4,4><<<dim3(9216),blk,0,stream>>>(XPB,120,0,  XP1,60,0,  YS1, 0);
    attn_m<8,1><<<dim3(9216),blk,0,stream>>>(XPB,120,40, XP1,60,20, YS1,20);
    attn_m<12,1><<<dim3(4096),blk,0,stream>>>(XPB,120,80,XP1,60,40, YS1,40);
    // S10: out = po1(ys1) + x3                    f32 final
    conv_g<60,60,0,true,false,true,true,false><<<gconv,blk,0,stream>>>(
        YS1, W10, AB10, CCB, OUTF);
}

// Round 10
// 981.872 us; speedup vs baseline: 1.3248x; 1.3248x over previous
//
#include <hip/hip_runtime.h>
#include <math.h>

constexpr int B_ = 4, C_ = 60, H_ = 384, W_ = 384;
constexpr int HW_ = H_ * W_;
constexpr int NC_ = B_ * C_ * HW_;   // 35,389,440
constexpr int NE_ = B_ * 120 * HW_;  // 70,778,880

typedef __attribute__((ext_vector_type(8))) short short8;
typedef __attribute__((ext_vector_type(4))) float f32x4;
typedef __attribute__((ext_vector_type(4))) unsigned short u16x4;

__device__ __forceinline__ unsigned short f2b(float f) {
    unsigned u = __builtin_bit_cast(unsigned, f);
    unsigned r = (u + 0x7fff + ((u >> 16) & 1)) >> 16;
    return (unsigned short)r;
}
__device__ __forceinline__ float b2f(unsigned short s) {
    return __builtin_bit_cast(float, (unsigned)s << 16);
}

// bijective XCD-chunk swizzle (m204): consecutive output ids stay on one XCD
__device__ __forceinline__ int xcd_swz(int bid, int nwg) {
    const int q = nwg >> 3, r = nwg & 7;
    const int xcd = bid & 7, off = bid >> 3;
    return (xcd < r ? xcd * (q + 1) : r * (q + 1) + (xcd - r) * q) + off;
}

// ---------------------------------------------------------------------------
// Weight prep: fp32 [COUT][CIN] -> bf16 [MP][KP], zero-pad, XOR-swizzle
// ---------------------------------------------------------------------------
struct PrepJobs {
    const float* src[8];
    unsigned short* dst[8];
    int cin[8];
    int cout[8];
};

__global__ __launch_bounds__(256) void prep_all(PrepJobs J)
{
    int bid = blockIdx.x;
    #pragma unroll 1
    for (int j = 0; j < 8; ++j) {
        const int KP = J.cin[j]  > 64 ? 128 : 64;
        const int MP = J.cout[j] > 64 ? 128 : 64;
        const int nb = MP * KP / 256;
        if (bid < nb) {
            const int i = bid * 256 + threadIdx.x;
            const int o = i / KP, c = i - o * KP;
            const float v = (o < J.cout[j] && c < J.cin[j]) ? J.src[j][o * J.cin[j] + c] : 0.f;
            J.dst[j][o * KP + (c ^ ((o & 7) << 3))] = f2b(v);
            return;
        }
        bid -= nb;
    }
}

// ---------------------------------------------------------------------------
// Epilogue affine prep: fold bias (+BN) into per-channel A*acc + B.
// ---------------------------------------------------------------------------
struct ABJobs {
    const float* bias[8];
    const float* g[8];
    const float* bb[8];
    const float* m[8];
    const float* v[8];
    float* dst[8];
    int cout[8];
};

__global__ __launch_bounds__(256) void prep_ab(ABJobs J)
{
    const int j = blockIdx.x;
    const int n = J.cout[j];
    for (int o = threadIdx.x; o < n; o += 256) {
        float A = 1.f, Bv = J.bias[j][o];
        if (J.g[j]) {
            const float s = J.g[j][o] * rsqrtf(J.v[j][o] + 1e-5f);
            A  = s;
            Bv = (Bv - J.m[j][o]) * s + J.bb[j][o];
        }
        J.dst[j][o]     = A;
        J.dst[j][n + o] = Bv;
    }
}

// ---------------------------------------------------------------------------
// conv1x1 via MFMA, 128-px tile, 4 waves. D = [px][ch] orientation.
// ---------------------------------------------------------------------------
template<int KP>
__device__ __forceinline__ int lds_off(int px, int cb) {
    return px * (KP * 2) + (cb ^ ((px & 7) << 4) ^ (((px >> 3) & 1) << 6));
}

template<int CIN, int COUT, int GSH, bool SRCB, bool RELU, bool RESID,
         bool RESIDB, bool OUTB>
__global__ __launch_bounds__(256, 4)
void conv_g(const void* __restrict__ in_, const unsigned short* __restrict__ wp,
            const float* __restrict__ AB,
            const void* __restrict__ resid_, void* __restrict__ out_)
{
    constexpr int KP  = CIN  > 64 ? 128 : 64;
    constexpr int MP  = COUT > 64 ? 128 : 64;
    constexpr int NNT = MP / 16;
    constexpr int KBL = KP / 32;
    __shared__ __align__(16) char xlds[128 * KP * 2];

    const int tid = threadIdx.x;
    const int n0  = blockIdx.x * 128;
    const int b   = n0 / HW_;
    const int p0  = n0 - b * HW_;
    const int hh  = p0 / W_;
    const int ww0 = p0 - hh * W_;

    // ---- staging: task = (oct | pr); pr in low 4 bits ----
    for (int task = tid; task < (KP / 2) * 16; task += 256) {
        const int oct = (task >> 4) & 15;
        const int pr  = (task & 15) | ((task >> 8) << 4);
        const int c0  = pr * 2;
        const int s0  = oct * 8;

        if (c0 >= CIN) {
            #pragma unroll
            for (int i = 0; i < 8; ++i)
                *(unsigned*)(xlds + lds_off<KP>(s0 + i, c0 * 2)) = 0u;
            continue;
        }

        int dh = 0, dw = 0;
        if (GSH > 0) {
            const int grp = c0 / GSH;
            dh = (grp == 2) ? 1 : ((grp == 3) ? -1 : 0);
            dw = (grp == 0) ? 1 : ((grp == 1) ? -1 : 0);
        }
        const int h2 = hh + dh;
        const bool vh = (unsigned)h2 < (unsigned)H_;
        const long eoff = (long)(b * CIN + c0) * HW_ + h2 * W_ + ww0 + s0;

        unsigned short va[8], vb[8];
        if (vh) {
            if constexpr (SRCB) {
                const unsigned short* p = (const unsigned short*)in_;
                short8 A = *(const short8*)(p + eoff);
                short8 Bv = *(const short8*)(p + eoff + HW_);
                #pragma unroll
                for (int i = 0; i < 8; ++i) { va[i] = (unsigned short)A[i]; vb[i] = (unsigned short)Bv[i]; }
            } else {
                const float* p = (const float*)in_;
                f32x4 A0 = *(const f32x4*)(p + eoff);
                f32x4 A1 = *(const f32x4*)(p + eoff + 4);
                f32x4 B0 = *(const f32x4*)(p + eoff + HW_);
                f32x4 B1 = *(const f32x4*)(p + eoff + HW_ + 4);
                #pragma unroll
                for (int i = 0; i < 4; ++i) {
                    va[i] = f2b(A0[i]); va[i + 4] = f2b(A1[i]);
                    vb[i] = f2b(B0[i]); vb[i + 4] = f2b(B1[i]);
                }
            }
        } else {
            #pragma unroll
            for (int i = 0; i < 8; ++i) { va[i] = 0; vb[i] = 0; }
        }
        #pragma unroll
        for (int i = 0; i < 8; ++i) {
            const int px = s0 + i - dw;
            if ((unsigned)px < 128u) {
                const unsigned v = (unsigned)va[i] | ((unsigned)vb[i] << 16);
                *(unsigned*)(xlds + lds_off<KP>(px, c0 * 2)) = v;
            }
        }
        if (GSH > 0 && dw != 0) {
            const bool hndl = (dw == 1) ? (oct == 15) : (oct == 0);
            if (hndl) {
                const int px_e = (dw == 1) ? 127 : 0;
                const int w_abs = ww0 + px_e + dw;
                unsigned short ua = 0, ub = 0;
                if (vh && (unsigned)w_abs < (unsigned)W_) {
                    const long e2 = (long)(b * CIN + c0) * HW_ + h2 * W_ + w_abs;
                    if constexpr (SRCB) {
                        ua = ((const unsigned short*)in_)[e2];
                        ub = ((const unsigned short*)in_)[e2 + HW_];
                    } else {
                        ua = f2b(((const float*)in_)[e2]);
                        ub = f2b(((const float*)in_)[e2 + HW_]);
                    }
                }
                *(unsigned*)(xlds + lds_off<KP>(px_e, c0 * 2)) =
                    (unsigned)ua | ((unsigned)ub << 16);
            }
        }
    }
    __syncthreads();

    // ---- MFMA: A = X from LDS (px rows), B = W from global (ch rows) ----
    const int wv = tid >> 6, lo = tid & 15, hi = (tid & 63) >> 4;
    f32x4 acc[2][NNT];
    #pragma unroll
    for (int mt = 0; mt < 2; ++mt)
        #pragma unroll
        for (int nt = 0; nt < NNT; ++nt) acc[mt][nt] = f32x4{0.f, 0.f, 0.f, 0.f};

    #pragma unroll
    for (int kb = 0; kb < KBL; ++kb) {
        short8 a[2], bb[NNT];
        #pragma unroll
        for (int mt = 0; mt < 2; ++mt) {
            const int row = wv * 32 + mt * 16 + lo;
            a[mt] = *(const short8*)(xlds + lds_off<KP>(row, kb * 64 + hi * 16));
        }
        #pragma unroll
        for (int nt = 0; nt < NNT; ++nt) {
            const int row = nt * 16 + lo;
            bb[nt] = *(const short8*)((const char*)wp +
                      row * (KP * 2) + ((kb * 64 + hi * 16) ^ ((row & 7) << 4)));
        }
        #pragma unroll
        for (int mt = 0; mt < 2; ++mt)
            #pragma unroll
            for (int nt = 0; nt < NNT; ++nt)
                acc[mt][nt] = __builtin_amdgcn_mfma_f32_16x16x32_bf16(
                    a[mt], bb[nt], acc[mt][nt], 0, 0, 0);
    }

    // ---- epilogue: lane holds 4 consecutive px of channel nt*16+lo ----
    #pragma unroll
    for (int mt = 0; mt < 2; ++mt) {
        const int px0 = p0 + wv * 32 + mt * 16 + hi * 4;
        #pragma unroll
        for (int nt = 0; nt < NNT; ++nt) {
            const int ch = nt * 16 + lo;
            if (ch < COUT) {
                const long oi = (long)(b * COUT + ch) * HW_ + px0;
                float v[4];
                f32x4 rf;
                u16x4 rb;
                if (RESID) {
                    if (RESIDB) rb = *(const u16x4*)((const unsigned short*)resid_ + oi);
                    else        rf = *(const f32x4*)((const float*)resid_ + oi);
                }
                #pragma unroll
                for (int r = 0; r < 4; ++r) {
                    float t = fmaf(acc[mt][nt][r], AB[ch], AB[COUT + ch]);
                    if (RELU) t = fmaxf(t, 0.f);
                    if (RESID) t += RESIDB ? b2f(rb[r]) : rf[r];
                    v[r] = t;
                }
                if (OUTB) {
                    u16x4 o4;
                    #pragma unroll
                    for (int r = 0; r < 4; ++r) o4[r] = f2b(v[r]);
                    *(u16x4*)((unsigned short*)out_ + oi) = o4;
                } else {
                    *(f32x4*)((float*)out_ + oi) = f32x4{v[0], v[1], v[2], v[3]};
                }
            }
        }
    }
}

// ---------------------------------------------------------------------------
// MFMA window attention (R8 scalar gather + XCD-chunk block swizzle).
// ---------------------------------------------------------------------------
template<int WS, int WPB>
__global__ __launch_bounds__(256)
void attn_m(const unsigned short* __restrict__ qsrc, int qC, int qbase,
            const unsigned short* __restrict__ vsrc, int vC, int vbase,
            unsigned short* __restrict__ out, int obase)
{
    constexpr int P     = WS * WS;
    constexpr int NMT   = P / 16;
    constexpr int S     = WS / 2;
    constexpr int WGX   = W_ / WS;
    constexpr int WGY   = H_ / WS;
    constexpr int NWIN  = WGY * WGX;
    constexpr int QP    = 40;
    constexpr int KP2   = ((P + 31) / 32) * 32;
    constexpr int VP    = KP2 + 8;
    constexpr int KB2   = KP2 / 32;
    constexpr int TILES = WPB * NMT;

    __shared__ __align__(16) unsigned short Qs[WPB * P * QP];
    __shared__ __align__(16) unsigned short VTs[WPB * 32 * VP];
    __shared__ __align__(16) unsigned short Ps[WPB * P * VP];
    __shared__ float rs[WPB * P];

    const int tid = threadIdx.x;
    const int blk = xcd_swz(blockIdx.x, gridDim.x);   // L2-locality swizzle

    // ---- zero pads ----
    for (int i = tid; i < WPB * P * 6; i += 256) {
        const int row = i / 6, j = i - (i / 6) * 6;
        *(unsigned*)&Qs[row * QP + 20 + 2 * j] = 0u;
    }
    for (int i = tid; i < WPB * 12 * (KP2 / 2); i += 256) {
        const int rr = i / (KP2 / 2), j = i - rr * (KP2 / 2);
        const int win = rr / 12, ch = 20 + (rr - (rr / 12) * 12);
        *(unsigned*)&VTs[(win * 32 + ch) * VP + 2 * j] = 0u;
    }
    if constexpr (KP2 > P) {
        for (int i = tid; i < WPB * 20 * ((KP2 - P) / 2); i += 256) {
            const int rr = i / ((KP2 - P) / 2), j = i - rr * ((KP2 - P) / 2);
            const int win = rr / 20, ch = rr - (rr / 20) * 20;
            *(unsigned*)&VTs[(win * 32 + ch) * VP + P + 2 * j] = 0u;
        }
        for (int i = tid; i < WPB * P * ((KP2 - P) / 2); i += 256) {
            const int row = i / ((KP2 - P) / 2), j = i - row * ((KP2 - P) / 2);
            *(unsigned*)&Ps[row * VP + P + 2 * j] = 0u;
        }
    }
    // ---- fill Q and VT (scalar gather, R8 form) ----
    for (int e = tid; e < WPB * P * 20; e += 256) {
        const int win = e / (P * 20);
        const int rem = e - win * (P * 20);
        const int ch  = rem / P;
        const int pos = rem - ch * P;
        const int gw  = blk * WPB + win;
        const int b   = gw / NWIN;
        const int rwin = gw - b * NWIN;
        const int wh = rwin / WGX, ww = rwin - (rwin / WGX) * WGX;
        const int pr = pos / WS,  pc = pos - (pos / WS) * WS;
        int hs = wh * WS + pr + S; if (hs >= H_) hs -= H_;
        int wd = ww * WS + pc + S; if (wd >= W_) wd -= W_;
        const long off = (long)hs * W_ + wd;
        Qs [(win * P  + pos) * QP + ch ] = qsrc[(long)(b * qC + qbase + ch) * HW_ + off];
        VTs[(win * 32 + ch ) * VP + pos] = vsrc[(long)(b * vC + vbase + ch) * HW_ + off];
    }
    __syncthreads();

    const int wv = tid >> 6, lo = tid & 15, hi = (tid & 63) >> 4;

    // ---- phase 1: S = QQ^T, P = exp(S), rowsums ----
    for (int t = wv; t < TILES; t += 4) {
        const int win = t / NMT, mt = t - (t / NMT) * NMT;
        const unsigned short* Qw = Qs + win * P * QP;
        unsigned short* Pw = Ps + win * P * VP;

        const short8 af = *(const short8*)(Qw + (mt * 16 + lo) * QP + hi * 8);
        f32x4 a1[NMT];
        #pragma unroll
        for (int nt = 0; nt < NMT; ++nt) a1[nt] = f32x4{0.f, 0.f, 0.f, 0.f};
        #pragma unroll
        for (int nt = 0; nt < NMT; ++nt) {
            const short8 bf = *(const short8*)(Qw + (nt * 16 + lo) * QP + hi * 8);
            a1[nt] = __builtin_amdgcn_mfma_f32_16x16x32_bf16(af, bf, a1[nt], 0, 0, 0);
        }
        float psum[4] = {0.f, 0.f, 0.f, 0.f};
        #pragma unroll
        for (int nt = 0; nt < NMT; ++nt) {
            #pragma unroll
            for (int r = 0; r < 4; ++r) {
                const float p = __expf(a1[nt][r]);
                psum[r] += p;
                Pw[(mt * 16 + hi * 4 + r) * VP + nt * 16 + lo] = f2b(p);
            }
        }
        #pragma unroll
        for (int r = 0; r < 4; ++r) {
            psum[r] += __shfl_xor(psum[r], 1);
            psum[r] += __shfl_xor(psum[r], 2);
            psum[r] += __shfl_xor(psum[r], 4);
            psum[r] += __shfl_xor(psum[r], 8);
        }
        if (lo == 0) {
            #pragma unroll
            for (int r = 0; r < 4; ++r)
                rs[win * P + mt * 16 + hi * 4 + r] = psum[r];
        }
    }
    __syncthreads();

    // ---- phase 2: D = [ch][query]; A = VT (ch rows), B = P (query rows) ----
    for (int t = wv; t < TILES; t += 4) {
        const int win = t / NMT, qt = t - (t / NMT) * NMT;
        const unsigned short* Vw = VTs + win * 32 * VP;
        const unsigned short* Pw = Ps + win * P * VP;

        f32x4 a2[2];
        a2[0] = f32x4{0.f, 0.f, 0.f, 0.f};
        a2[1] = f32x4{0.f, 0.f, 0.f, 0.f};
        #pragma unroll
        for (int kb = 0; kb < KB2; ++kb) {
            const short8 bf = *(const short8*)(Pw + (qt * 16 + lo) * VP + kb * 32 + hi * 8);
            #pragma unroll
            for (int m2 = 0; m2 < 2; ++m2) {
                const short8 af = *(const short8*)(Vw + (m2 * 16 + lo) * VP + kb * 32 + hi * 8);
                a2[m2] = __builtin_amdgcn_mfma_f32_16x16x32_bf16(af, bf, a2[m2], 0, 0, 0);
            }
        }
        const int gw = blk * WPB + win;
        const int b  = gw / NWIN;
        const int rwin = gw - b * NWIN;
        const int wh = rwin / WGX, ww = rwin - (rwin / WGX) * WGX;

        const int row = qt * 16 + lo;
        const float inv = 1.f / rs[win * P + row];
        const int pr = row / WS, pc = row - (row / WS) * WS;
        int hs = wh * WS + pr + S; if (hs >= H_) hs -= H_;
        int wd = ww * WS + pc + S; if (wd >= W_) wd -= W_;
        const long pbase = (long)(b * 60 + obase) * HW_ + (long)hs * W_ + wd;
        #pragma unroll
        for (int m2 = 0; m2 < 2; ++m2) {
            #pragma unroll
            for (int r = 0; r < 4; ++r) {
                const int ch = m2 * 16 + hi * 4 + r;
                if (ch < 20)
                    out[pbase + (long)ch * HW_] = f2b(a2[m2][r] * inv);
            }
        }
    }
}

// ---------------------------------------------------------------------------
extern "C" void kernel_launch(void* const* d_in, const int* in_sizes, int n_in,
                              void* d_out, int out_size, void* d_ws, size_t ws_size,
                              hipStream_t stream)
{
    const float* x     = (const float*)d_in[0];
    const float* l0w0  = (const float*)d_in[1];
    const float* l0b0  = (const float*)d_in[2];
    const float* l0w1  = (const float*)d_in[3];
    const float* l0b1  = (const float*)d_in[4];
    const float* g0piw = (const float*)d_in[5];
    const float* g0pib = (const float*)d_in[6];
    const float* g0bng = (const float*)d_in[7];
    const float* g0bnb = (const float*)d_in[8];
    const float* g0bnm = (const float*)d_in[9];
    const float* g0bnv = (const float*)d_in[10];
    const float* g0pow = (const float*)d_in[11];
    const float* g0pob = (const float*)d_in[12];
    const float* l1w0  = (const float*)d_in[13];
    const float* l1b0  = (const float*)d_in[14];
    const float* l1w1  = (const float*)d_in[15];
    const float* l1b1  = (const float*)d_in[16];
    const float* g1piw = (const float*)d_in[17];
    const float* g1pib = (const float*)d_in[18];
    const float* g1bng = (const float*)d_in[19];
    const float* g1bnb = (const float*)d_in[20];
    const float* g1bnm = (const float*)d_in[21];
    const float* g1bnv = (const float*)d_in[22];
    const float* g1pow = (const float*)d_in[23];
    const float* g1pob = (const float*)d_in[24];

    // ws: HID(NE_) | XPB(NE_) | XP1(NC_) | YS1(NC_) | CCB(NC_) | WP | AB
    unsigned short* HID = (unsigned short*)d_ws;
    unsigned short* XPB = HID + NE_;
    unsigned short* XP1 = XPB + NE_;
    unsigned short* YS1 = XP1 + NC_;
    unsigned short* CCB = YS1 + NC_;
    unsigned short* WP  = CCB + NC_;
    float*          ABF = (float*)(WP + 53248);
    float* OUTF  = (float*)d_out;
    unsigned short* YS0 = (unsigned short*)d_out;

    unsigned short* W1  = WP;
    unsigned short* W2  = WP + 8192;
    unsigned short* W3  = WP + 16384;
    unsigned short* W5  = WP + 24576;
    unsigned short* W6  = WP + 28672;
    unsigned short* W7  = WP + 36864;
    unsigned short* W8  = WP + 45056;
    unsigned short* W10 = WP + 49152;

    float* AB1  = ABF;
    float* AB2  = ABF + 240;
    float* AB3  = ABF + 360;
    float* AB5  = ABF + 600;
    float* AB6  = ABF + 720;
    float* AB7  = ABF + 960;
    float* AB8  = ABF + 1080;
    float* AB10 = ABF + 1200;

    PrepJobs J;
    J.src[0]=l0w0;  J.dst[0]=W1;  J.cin[0]=60;  J.cout[0]=120;
    J.src[1]=l0w1;  J.dst[1]=W2;  J.cin[1]=120; J.cout[1]=60;
    J.src[2]=g0piw; J.dst[2]=W3;  J.cin[2]=60;  J.cout[2]=120;
    J.src[3]=g0pow; J.dst[3]=W5;  J.cin[3]=60;  J.cout[3]=60;
    J.src[4]=l1w0;  J.dst[4]=W6;  J.cin[4]=60;  J.cout[4]=120;
    J.src[5]=l1w1;  J.dst[5]=W7;  J.cin[5]=120; J.cout[5]=60;
    J.src[6]=g1piw; J.dst[6]=W8;  J.cin[6]=60;  J.cout[6]=60;
    J.src[7]=g1pow; J.dst[7]=W10; J.cin[7]=60;  J.cout[7]=60;
    prep_all<<<208, 256, 0, stream>>>(J);

    ABJobs A;
    for (int j = 0; j < 8; ++j) { A.g[j]=nullptr; A.bb[j]=nullptr; A.m[j]=nullptr; A.v[j]=nullptr; }
    A.bias[0]=l0b0;  A.dst[0]=AB1;  A.cout[0]=120;
    A.bias[1]=l0b1;  A.dst[1]=AB2;  A.cout[1]=60;
    A.bias[2]=g0pib; A.dst[2]=AB3;  A.cout[2]=120; A.g[2]=g0bng; A.bb[2]=g0bnb; A.m[2]=g0bnm; A.v[2]=g0bnv;
    A.bias[3]=g0pob; A.dst[3]=AB5;  A.cout[3]=60;
    A.bias[4]=l1b0;  A.dst[4]=AB6;  A.cout[4]=120;
    A.bias[5]=l1b1;  A.dst[5]=AB7;  A.cout[5]=60;
    A.bias[6]=g1pib; A.dst[6]=AB8;  A.cout[6]=60;  A.g[6]=g1bng; A.bb[6]=g1bnb; A.m[6]=g1bnm; A.v[6]=g1bnv;
    A.bias[7]=g1pob; A.dst[7]=AB10; A.cout[7]=60;
    prep_ab<<<8, 256, 0, stream>>>(A);

    dim3 blk(256);
    dim3 gconv(B_ * HW_ / 128);   // 4608

    // template args: CIN, COUT, GSH, SRCB, RELU, RESID, RESIDB, OUTB
    // S1: hid0 = relu(conv(shift5(x)))            f32 -> bf16
    conv_g<60,120,12,false,true,false,false,true><<<gconv,blk,0,stream>>>(
        x, W1, AB1, nullptr, HID);
    // S2: x1 = conv(shift5(hid0)) + x             bf16+f32resid -> bf16 CCB
    conv_g<120,60,24,true,false,true,false,true><<<gconv,blk,0,stream>>>(
        HID, W2, AB2, x, CCB);
    // S3: xp0 = BN(pi0(x1)) -> XPB bf16 (120ch)
    conv_g<60,120,0,true,false,false,false,true><<<gconv,blk,0,stream>>>(
        CCB, W3, AB3, nullptr, XPB);
    // S4: gmsa_first attention -> YS0 (d_out scratch)
    attn_m<4,4><<<dim3(9216),blk,0,stream>>>(XPB,120,0,   XPB,120,20,  YS0, 0);
    attn_m<8,1><<<dim3(9216),blk,0,stream>>>(XPB,120,40,  XPB,120,60,  YS0,20);
    attn_m<12,1><<<dim3(4096),blk,0,stream>>>(XPB,120,80, XPB,120,100, YS0,40);
    // S5: x2 = po0(ys0) + x1                      bf16 -> bf16 CCB (in place)
    conv_g<60,60,0,true,false,true,true,true><<<gconv,blk,0,stream>>>(
        YS0, W5, AB5, CCB, CCB);
    // S6: hid1 = relu(conv(shift5(x2)))
    conv_g<60,120,12,true,true,false,false,true><<<gconv,blk,0,stream>>>(
        CCB, W6, AB6, nullptr, HID);
    // S7: x3 = conv(shift5(hid1)) + x2            (CCB in place)
    conv_g<120,60,24,true,false,true,true,true><<<gconv,blk,0,stream>>>(
        HID, W7, AB7, CCB, CCB);
    // S8: xp1 = BN(pi1(x3)) -> XP1 bf16 (60ch; XPB stays intact for S9 q)
    conv_g<60,60,0,true,false,false,false,true><<<gconv,blk,0,stream>>>(
        CCB, W8, AB8, nullptr, XP1);
    // S9: gmsa_shared attention (q from XPB xp0 q-channels, v from XP1)
    attn_m<4,4><<<dim3(9216),blk,0,stream>>>(XPB,120,0,  XP1,60,0,  YS1, 0);
    attn_m<8,1><<<dim3(9216),blk,0,stream>>>(XPB,120,40, XP1,60,20, YS1,20);
    attn_m<12,1><<<dim3(4096),blk,0,stream>>>(XPB,120,80,XP1,60,40, YS1,40);
    // S10: out = po1(ys1) + x3                    f32 final
    conv_g<60,60,0,true,false,true,true,false><<<gconv,blk,0,stream>>>(
        YS1, W10, AB10, CCB, OUTF);
}